// Round 11
// baseline (120.256 us; speedup 1.0000x reference)
//
#include <hip/hip_runtime.h>

#define N_NODES 50000
#define K_DEG   17
#define DIN     128
#define DOUT    64

typedef _Float16 f16;
typedef __attribute__((ext_vector_type(8))) short  short8;   // bf16 A/B frag (4 VGPR)
typedef __attribute__((ext_vector_type(4))) float  floatx4;  // C/D frag

// ---------------------------------------------------------------------------
// Batcher merge-exchange sorting network (compile-time; fully unrolls).
// ---------------------------------------------------------------------------
struct CEPair { unsigned char a, b; };

constexpr int net_count(int n) {
  int t = 0; while ((1 << t) < n) ++t;
  int cnt = 0;
  for (int p = 1 << (t - 1); p > 0; p >>= 1) {
    int q = 1 << (t - 1), r = 0, d = p;
    for (;;) {
      for (int i = 0; i < n - d; ++i)
        if ((i & p) == r) ++cnt;
      if (q == p) break;
      d = q - p; q >>= 1; r = p;
    }
  }
  return cnt;
}

template <int NP> struct NetArr { CEPair v[NP]; };

template <int NP>
constexpr NetArr<NP> net_pairs(int n) {
  NetArr<NP> out{};
  int t = 0; while ((1 << t) < n) ++t;
  int cnt = 0;
  for (int p = 1 << (t - 1); p > 0; p >>= 1) {
    int q = 1 << (t - 1), r = 0, d = p;
    for (;;) {
      for (int i = 0; i < n - d; ++i)
        if ((i & p) == r) {
          out.v[cnt].a = (unsigned char)i;
          out.v[cnt].b = (unsigned char)(i + d);
          ++cnt;
        }
      if (q == p) break;
      d = q - p; q >>= 1; r = p;
    }
  }
  return out;
}

constexpr int NP17 = net_count(K_DEG);   // 74 compare-exchanges for n=17

// ---------------------------------------------------------------------------
// bf16 helpers (RNE)
// ---------------------------------------------------------------------------
__device__ __forceinline__ unsigned int f2bf(float f) {
  union { float f; unsigned int u; } c; c.f = f;
  return (c.u + 0x7FFFu + ((c.u >> 16) & 1u)) >> 16;
}
__device__ __forceinline__ float bf2f(unsigned int b) {
  union { float f; unsigned int u; } c; c.u = b << 16;
  return c.f;
}

// ---------------------------------------------------------------------------
// Kernel 0: convert W -> frag-ordered bf16 hi/lo table T (32 KB). Frozen.
// ---------------------------------------------------------------------------
__global__ void convw_kernel(const float* __restrict__ W,
                             unsigned short* __restrict__ T) {
  const int flat = blockIdx.x * 256 + threadIdx.x;   // 0..8191
  const int j    = flat & 7;
  const int lane = (flat >> 3) & 63;
  const int pair = flat >> 9;                        // 0..15
  const int ks   = pair >> 2, nt = pair & 3;
  const int k    = ks * 32 + (lane >> 4) * 8 + j;
  const int n    = nt * 16 + (lane & 15);
  const float f  = W[k * DOUT + n];
  const unsigned int hb = f2bf(f);
  const float        lo = f - bf2f(hb);
  const unsigned int lb = f2bf(lo);
  T[flat]        = (unsigned short)hb;
  T[flat + 8192] = (unsigned short)lb;
}

// ---------------------------------------------------------------------------
// Kernel 1: xp = x @ W via bf16 MFMA, 3-term hi/lo split; fp16 output.
// Frozen since R4/R8 (near its memory floor).
// ---------------------------------------------------------------------------
__global__ __launch_bounds__(256) void gemm_kernel(
    const float* __restrict__ x, const unsigned short* __restrict__ T,
    f16* __restrict__ xp) {
  const int gwave = blockIdx.x * 4 + (threadIdx.x >> 6);
  if (gwave >= (N_NODES / 16)) return;
  const int lane = threadIdx.x & 63;
  const int r0 = gwave * 16;
  const int m  = lane & 15;     // A row within tile
  const int q  = lane >> 4;     // k-quad

  const float4* x4 = (const float4*)x;
  float4 xr[8];
  #pragma unroll
  for (int ks = 0; ks < 4; ++ks) {
    const int base = (r0 + m) * (DIN / 4) + ks * 8 + q * 2;
    xr[ks * 2 + 0] = x4[base + 0];
    xr[ks * 2 + 1] = x4[base + 1];
  }

  floatx4 acc[4];
  #pragma unroll
  for (int nt = 0; nt < 4; ++nt) acc[nt] = (floatx4){0.f, 0.f, 0.f, 0.f};

  const short8* Th = (const short8*)T;
  const short8* Tl = (const short8*)(T + 8192);

  #pragma unroll
  for (int ks = 0; ks < 4; ++ks) {
    short8 Bh[4], Bl[4];
    #pragma unroll
    for (int nt = 0; nt < 4; ++nt) {
      const int fi = (ks * 4 + nt) * 64 + lane;
      Bh[nt] = Th[fi];
      Bl[nt] = Tl[fi];
    }
    float f[8] = {xr[ks*2].x, xr[ks*2].y, xr[ks*2].z, xr[ks*2].w,
                  xr[ks*2+1].x, xr[ks*2+1].y, xr[ks*2+1].z, xr[ks*2+1].w};
    union { unsigned int i[4]; short8 s; } Ah, Al;
    #pragma unroll
    for (int r = 0; r < 4; ++r) {
      const unsigned int h0 = f2bf(f[2*r]),   h1 = f2bf(f[2*r+1]);
      const unsigned int l0 = f2bf(f[2*r]   - bf2f(h0));
      const unsigned int l1 = f2bf(f[2*r+1] - bf2f(h1));
      Ah.i[r] = h0 | (h1 << 16);
      Al.i[r] = l0 | (l1 << 16);
    }
    #pragma unroll
    for (int nt = 0; nt < 4; ++nt) {
      acc[nt] = __builtin_amdgcn_mfma_f32_16x16x32_bf16(Al.s, Bh[nt], acc[nt], 0, 0, 0);
      acc[nt] = __builtin_amdgcn_mfma_f32_16x16x32_bf16(Ah.s, Bl[nt], acc[nt], 0, 0, 0);
      acc[nt] = __builtin_amdgcn_mfma_f32_16x16x32_bf16(Ah.s, Bh[nt], acc[nt], 0, 0, 0);
    }
  }

  #pragma unroll
  for (int nt = 0; nt < 4; ++nt) {
    const int col = nt * 16 + m;
    #pragma unroll
    for (int r = 0; r < 4; ++r)
      xp[(r0 + q * 4 + r) * DOUT + col] = (f16)acc[nt][r];
  }
}

// ---------------------------------------------------------------------------
// Kernel 2: weighted per-dim median + scale + bias — TWO nodes per wave.
// R11: doubles per-wave MLP/ILP (34 independent gathers, 2 interleaved sort
// networks) to attack the latency-bound component diagnosed in R9/R10.
// Also: j*4 packed into the 13 zero LSBs of fp16-sourced fp32 (exact), LDS
// address recovered with one v_and_or (slot bases 256B-aligned). Per-node
// arithmetic is bit-identical to R10: min/max sort of LSB-indexed values,
// w permuted via one-copy-per-node LDS broadcast, cumsum sequential in
// sorted order, total = last cum, scale by total.
// ---------------------------------------------------------------------------
__global__ __launch_bounds__(256, 2) void median_kernel(
    const f16* __restrict__ xp, const int* __restrict__ col,
    const float* __restrict__ ew, const float* __restrict__ bias,
    float* __restrict__ out) {
  __shared__ float wlds[4 * 64];   // [wave][2 nodes][32 floats], 1 KB, 256B/wave

  const int wave = threadIdx.x >> 6;
  const int lane = threadIdx.x & 63;
  // node pair (2g, 2g+1); g wave-uniform by construction
  const int node0 = __builtin_amdgcn_readfirstlane((blockIdx.x * 4 + wave) * 2);

  const int*   cp = col + node0 * K_DEG;   // 34 contiguous ints  (uniform)
  const float* wp = ew  + node0 * K_DEG;   // 34 contiguous floats (uniform)

  // neighbor ids for both nodes -> SGPRs (wide s_loads)
  int c0[K_DEG], c1[K_DEG];
  #pragma unroll
  for (int j = 0; j < K_DEG; ++j) { c0[j] = cp[j]; c1[j] = cp[K_DEG + j]; }

  // 34 independent gathers issued back-to-back (2x MLP vs R10)
  float v0[K_DEG], v1[K_DEG];
  #pragma unroll
  for (int j = 0; j < K_DEG; ++j) v0[j] = (float)xp[c0[j] * DOUT + lane];
  #pragma unroll
  for (int j = 0; j < K_DEG; ++j) v1[j] = (float)xp[c1[j] * DOUT + lane];

  // stash both nodes' w: lanes 0..33 write one float each.
  // lane<17 -> node0 slot [0..16]; 17<=lane<34 -> node1 slot [32..48]
  {
    float* wb = wlds + wave * 64;
    if (lane < 2 * K_DEG) {
      const float wv = wp[lane];                       // coalesced 136B
      const int   a  = (lane < K_DEG) ? lane : (32 + lane - K_DEG);
      wb[a] = wv;
    }
  }

  const float bl = bias[lane];

  // pack j*4 into mantissa LSBs (exact: fp16->fp32 leaves 13 zero LSBs;
  // j*4 <= 64 fits in 7 bits). Extraction mask 0x7C.
  #pragma unroll
  for (int j = 0; j < K_DEG; ++j) {
    union { float f; unsigned int u; } a, b;
    a.f = v0[j]; a.u |= (unsigned)(j * 4); v0[j] = a.f;
    b.f = v1[j]; b.u |= (unsigned)(j * 4); v1[j] = b.f;
  }

  // two independent min/max-only sort networks, interleaved by scheduler
  constexpr NetArr<NP17> NET = net_pairs<NP17>(K_DEG);
  #pragma unroll
  for (int s = 0; s < NP17; ++s) {
    const int a = NET.v[s].a, b = NET.v[s].b;
    const float x0 = v0[a], y0 = v0[b];
    v0[a] = fminf(x0, y0);  v0[b] = fmaxf(x0, y0);
    const float x1 = v1[a], y1 = v1[b];
    v1[a] = fminf(x1, y1);  v1[b] = fmaxf(x1, y1);
  }

  // LDS byte bases (256B-aligned per wave; +128 for node1 slot)
  const unsigned base0 = (unsigned)(wave * 256);
  const unsigned base1 = base0 + 128;
  const char* wbytes = (const char*)wlds;

  // ---- node0 tail: sorted-w recovery, cumsum, selection, store ----
  {
    float run = 0.f, cum[K_DEG];
    #pragma unroll
    for (int j = 0; j < K_DEG; ++j) {
      union { float f; unsigned int u; } a; a.f = v0[j];
      const float swj = *(const float*)(wbytes + ((a.u & 0x7Cu) | base0));
      run += swj; cum[j] = run;
    }
    const float half = 0.5f * run;
    float med = v0[K_DEG - 1];
    #pragma unroll
    for (int j = K_DEG - 2; j >= 0; --j)
      med = (cum[j] >= half) ? v0[j] : med;
    out[node0 * DOUT + lane] = run * med + bl;
  }

  // ---- node1 tail ----
  {
    float run = 0.f, cum[K_DEG];
    #pragma unroll
    for (int j = 0; j < K_DEG; ++j) {
      union { float f; unsigned int u; } a; a.f = v1[j];
      const float swj = *(const float*)(wbytes + ((a.u & 0x7Cu) | base1));
      run += swj; cum[j] = run;
    }
    const float half = 0.5f * run;
    float med = v1[K_DEG - 1];
    #pragma unroll
    for (int j = K_DEG - 2; j >= 0; --j)
      med = (cum[j] >= half) ? v1[j] : med;
    out[(node0 + 1) * DOUT + lane] = run * med + bl;
  }
}

// ---------------------------------------------------------------------------
extern "C" void kernel_launch(void* const* d_in, const int* in_sizes, int n_in,
                              void* d_out, int out_size, void* d_ws, size_t ws_size,
                              hipStream_t stream) {
  const float* x    = (const float*)d_in[0];
  const int*   ei   = (const int*)d_in[1];
  const float* ew   = (const float*)d_in[2];
  const float* W    = (const float*)d_in[3];
  const float* bias = (const float*)d_in[4];
  float*       out  = (float*)d_out;

  f16*            xp = (f16*)d_ws;                              // 6.4 MB
  unsigned short* T  = (unsigned short*)((char*)d_ws + (size_t)N_NODES * DOUT * 2);
  const int*      colp = ei + (size_t)N_NODES * K_DEG;          // edge_index[1]

  convw_kernel<<<8192 / 256, 256, 0, stream>>>(W, T);
  gemm_kernel<<<(N_NODES / 16 + 3) / 4, 256, 0, stream>>>(x, T, xp);
  median_kernel<<<N_NODES / 8, 256, 0, stream>>>(xp, colp, ew, bias, out);
}

// Round 12
// 119.219 us; speedup vs baseline: 1.0087x; 1.0087x over previous
//
#include <hip/hip_runtime.h>

#define N_NODES 50000
#define K_DEG   17
#define DIN     128
#define DOUT    64

typedef _Float16 f16;
typedef __attribute__((ext_vector_type(8))) short  short8;   // bf16 A/B frag (4 VGPR)
typedef __attribute__((ext_vector_type(4))) float  floatx4;  // C/D frag

// ---------------------------------------------------------------------------
// Batcher merge-exchange sorting network (compile-time; fully unrolls).
// ---------------------------------------------------------------------------
struct CEPair { unsigned char a, b; };

constexpr int net_count(int n) {
  int t = 0; while ((1 << t) < n) ++t;
  int cnt = 0;
  for (int p = 1 << (t - 1); p > 0; p >>= 1) {
    int q = 1 << (t - 1), r = 0, d = p;
    for (;;) {
      for (int i = 0; i < n - d; ++i)
        if ((i & p) == r) ++cnt;
      if (q == p) break;
      d = q - p; q >>= 1; r = p;
    }
  }
  return cnt;
}

template <int NP> struct NetArr { CEPair v[NP]; };

template <int NP>
constexpr NetArr<NP> net_pairs(int n) {
  NetArr<NP> out{};
  int t = 0; while ((1 << t) < n) ++t;
  int cnt = 0;
  for (int p = 1 << (t - 1); p > 0; p >>= 1) {
    int q = 1 << (t - 1), r = 0, d = p;
    for (;;) {
      for (int i = 0; i < n - d; ++i)
        if ((i & p) == r) {
          out.v[cnt].a = (unsigned char)i;
          out.v[cnt].b = (unsigned char)(i + d);
          ++cnt;
        }
      if (q == p) break;
      d = q - p; q >>= 1; r = p;
    }
  }
  return out;
}

constexpr int NP17 = net_count(K_DEG);   // 74 compare-exchanges for n=17

// ---------------------------------------------------------------------------
// bf16 helpers (RNE)
// ---------------------------------------------------------------------------
__device__ __forceinline__ unsigned int f2bf(float f) {
  union { float f; unsigned int u; } c; c.f = f;
  return (c.u + 0x7FFFu + ((c.u >> 16) & 1u)) >> 16;
}
__device__ __forceinline__ float bf2f(unsigned int b) {
  union { float f; unsigned int u; } c; c.u = b << 16;
  return c.f;
}

// ---------------------------------------------------------------------------
// Kernel 0: convert W -> frag-ordered bf16 hi/lo table T (32 KB). Frozen.
// (Folding into gemm was evaluated and rejected: the frag layout is a
// transpose of W; direct per-wave reads would be 128 scattered dwords +
// ~768 convert VALU per wave. The 1.5us separate kernel is cheaper.)
// ---------------------------------------------------------------------------
__global__ void convw_kernel(const float* __restrict__ W,
                             unsigned short* __restrict__ T) {
  const int flat = blockIdx.x * 256 + threadIdx.x;   // 0..8191
  const int j    = flat & 7;
  const int lane = (flat >> 3) & 63;
  const int pair = flat >> 9;                        // 0..15
  const int ks   = pair >> 2, nt = pair & 3;
  const int k    = ks * 32 + (lane >> 4) * 8 + j;
  const int n    = nt * 16 + (lane & 15);
  const float f  = W[k * DOUT + n];
  const unsigned int hb = f2bf(f);
  const float        lo = f - bf2f(hb);
  const unsigned int lb = f2bf(lo);
  T[flat]        = (unsigned short)hb;
  T[flat + 8192] = (unsigned short)lb;
}

// ---------------------------------------------------------------------------
// Kernel 1: xp = x @ W via bf16 MFMA, 3-term hi/lo split; fp16 output.
// Frozen since R4/R8 (near its memory floor).
// ---------------------------------------------------------------------------
__global__ __launch_bounds__(256) void gemm_kernel(
    const float* __restrict__ x, const unsigned short* __restrict__ T,
    f16* __restrict__ xp) {
  const int gwave = blockIdx.x * 4 + (threadIdx.x >> 6);
  if (gwave >= (N_NODES / 16)) return;
  const int lane = threadIdx.x & 63;
  const int r0 = gwave * 16;
  const int m  = lane & 15;     // A row within tile
  const int q  = lane >> 4;     // k-quad

  const float4* x4 = (const float4*)x;
  float4 xr[8];
  #pragma unroll
  for (int ks = 0; ks < 4; ++ks) {
    const int base = (r0 + m) * (DIN / 4) + ks * 8 + q * 2;
    xr[ks * 2 + 0] = x4[base + 0];
    xr[ks * 2 + 1] = x4[base + 1];
  }

  floatx4 acc[4];
  #pragma unroll
  for (int nt = 0; nt < 4; ++nt) acc[nt] = (floatx4){0.f, 0.f, 0.f, 0.f};

  const short8* Th = (const short8*)T;
  const short8* Tl = (const short8*)(T + 8192);

  #pragma unroll
  for (int ks = 0; ks < 4; ++ks) {
    short8 Bh[4], Bl[4];
    #pragma unroll
    for (int nt = 0; nt < 4; ++nt) {
      const int fi = (ks * 4 + nt) * 64 + lane;
      Bh[nt] = Th[fi];
      Bl[nt] = Tl[fi];
    }
    float f[8] = {xr[ks*2].x, xr[ks*2].y, xr[ks*2].z, xr[ks*2].w,
                  xr[ks*2+1].x, xr[ks*2+1].y, xr[ks*2+1].z, xr[ks*2+1].w};
    union { unsigned int i[4]; short8 s; } Ah, Al;
    #pragma unroll
    for (int r = 0; r < 4; ++r) {
      const unsigned int h0 = f2bf(f[2*r]),   h1 = f2bf(f[2*r+1]);
      const unsigned int l0 = f2bf(f[2*r]   - bf2f(h0));
      const unsigned int l1 = f2bf(f[2*r+1] - bf2f(h1));
      Ah.i[r] = h0 | (h1 << 16);
      Al.i[r] = l0 | (l1 << 16);
    }
    #pragma unroll
    for (int nt = 0; nt < 4; ++nt) {
      acc[nt] = __builtin_amdgcn_mfma_f32_16x16x32_bf16(Al.s, Bh[nt], acc[nt], 0, 0, 0);
      acc[nt] = __builtin_amdgcn_mfma_f32_16x16x32_bf16(Ah.s, Bl[nt], acc[nt], 0, 0, 0);
      acc[nt] = __builtin_amdgcn_mfma_f32_16x16x32_bf16(Ah.s, Bh[nt], acc[nt], 0, 0, 0);
    }
  }

  #pragma unroll
  for (int nt = 0; nt < 4; ++nt) {
    const int col = nt * 16 + m;
    #pragma unroll
    for (int r = 0; r < 4; ++r)
      xp[(r0 + q * 4 + r) * DOUT + col] = (f16)acc[nt][r];
  }
}

// ---------------------------------------------------------------------------
// Kernel 2: weighted per-dim median + scale + bias.
// R12: R10 per-wave body (1 node/wave, lowest VGPR — best measured), but
// 512-thread blocks (8 waves) to test the dispatch/occupancy-cap hypothesis
// (occupancy sat at ~55% with 36 VGPR and tiny LDS in R1-R6 — nothing in
// {VGPR,LDS,block} explains it; short 4-wave blocks may be CP-limited).
// Micro: j*4 packed into the 13 zero LSBs of fp16-sourced fp32 (exact);
// LDS recovery addr = one v_and_or (wave slots 128B-aligned); gather for
// j=16 issued first (first CE is (0,16)). Arithmetic bit-identical to
// R10/R11: min/max sort, one-copy-per-node w broadcast, cumsum sequential
// in sorted order, total = last cum, scale by total.
// ---------------------------------------------------------------------------
__global__ __launch_bounds__(512) void median_kernel(
    const f16* __restrict__ xp, const int* __restrict__ col,
    const float* __restrict__ ew, const float* __restrict__ bias,
    float* __restrict__ out) {
  __shared__ float wlds[8 * 32];             // [wave][32 floats] = 128B/wave

  const int wave = threadIdx.x >> 6;
  const int lane = threadIdx.x & 63;
  // wave-uniform by construction; readfirstlane makes it provably uniform
  const int node = __builtin_amdgcn_readfirstlane(blockIdx.x * 8 + wave);

  const int*   cp = col + node * K_DEG;      // uniform address -> s_load
  const float* wp = ew  + node * K_DEG;      // uniform address

  // neighbor ids (uniform -> SGPRs)
  int c[K_DEG];
  #pragma unroll
  for (int j = 0; j < K_DEG; ++j) c[j] = cp[j];

  // gathers: j=16 issued first (earliest consumer in the network), then 0..15
  float v[K_DEG];
  v[16] = (float)xp[c[16] * DOUT + lane];
  #pragma unroll
  for (int j = 0; j < K_DEG - 1; ++j)
    v[j] = (float)xp[c[j] * DOUT + lane];    // 128B coalesced fp16 gather

  // stash w ONCE per node: lanes 0..16 write one float each
  float* wl = wlds + wave * 32;
  if (lane < K_DEG) wl[lane] = wp[lane];

  const float bl = bias[lane];

  // pack j*4 into mantissa LSBs (exact: fp16->fp32 leaves 13 zero LSBs;
  // j*4 <= 64 fits bits [2..6]); extraction mask 0x7C as byte offset
  #pragma unroll
  for (int j = 0; j < K_DEG; ++j) {
    union { float f; unsigned int u; } c2; c2.f = v[j];
    c2.u |= (unsigned)(j * 4);
    v[j] = c2.f;
  }

  // sort v ascending — min/max-only compile-time Batcher network (2 ops/CE)
  constexpr NetArr<NP17> NET = net_pairs<NP17>(K_DEG);
  #pragma unroll
  for (int s = 0; s < NP17; ++s) {
    const int a = NET.v[s].a, b = NET.v[s].b;
    const float va = v[a], vb = v[b];
    v[a] = fminf(va, vb);
    v[b] = fmaxf(va, vb);
  }

  // recover w in sorted order (broadcast LDS read, conflict-free) + cumsum
  const unsigned base = (unsigned)(wave * 128);   // 128B-aligned -> OR exact
  const char* wbytes = (const char*)wlds;
  float run = 0.f, cum[K_DEG];
  #pragma unroll
  for (int j = 0; j < K_DEG; ++j) {
    union { float f; unsigned int u; } c2; c2.f = v[j];
    const float swj = *(const float*)(wbytes + ((c2.u & 0x7Cu) | base));
    run += swj; cum[j] = run;                // exact reference cumsum order
  }
  const float half = 0.5f * run;             // run == total == cum[-1]

  // first sorted position with cum >= half: backward cndmask scan
  float med = v[K_DEG - 1];
  #pragma unroll
  for (int j = K_DEG - 2; j >= 0; --j)
    med = (cum[j] >= half) ? v[j] : med;

  // scale by total (== row_sum up to ~1 ulp; output shift ~1e-5, harmless)
  out[node * DOUT + lane] = run * med + bl;
}

// ---------------------------------------------------------------------------
extern "C" void kernel_launch(void* const* d_in, const int* in_sizes, int n_in,
                              void* d_out, int out_size, void* d_ws, size_t ws_size,
                              hipStream_t stream) {
  const float* x    = (const float*)d_in[0];
  const int*   ei   = (const int*)d_in[1];
  const float* ew   = (const float*)d_in[2];
  const float* W    = (const float*)d_in[3];
  const float* bias = (const float*)d_in[4];
  float*       out  = (float*)d_out;

  f16*            xp = (f16*)d_ws;                              // 6.4 MB
  unsigned short* T  = (unsigned short*)((char*)d_ws + (size_t)N_NODES * DOUT * 2);
  const int*      colp = ei + (size_t)N_NODES * K_DEG;          // edge_index[1]

  convw_kernel<<<8192 / 256, 256, 0, stream>>>(W, T);
  gemm_kernel<<<(N_NODES / 16 + 3) / 4, 256, 0, stream>>>(x, T, xp);
  median_kernel<<<N_NODES / 8, 512, 0, stream>>>(xp, colp, ew, bias, out);
}